// Round 12
// baseline (363.573 us; speedup 1.0000x reference)
//
#include <hip/hip_runtime.h>
#include <stdint.h>

#define NROW 4096
#define NDIM 512
#define THRS 0.05f

typedef __attribute__((ext_vector_type(8))) __bf16 bf16x8;
typedef __attribute__((ext_vector_type(4))) float f32x4;

// ---------------- workspace layout ----------------
#define XHI_OFF  0ull
#define XHI_SZ   (3ull*4096ull*512ull*2ull)        // 12582912
#define XLO_OFF  (XHI_OFF + XHI_SZ)
#define XLO_SZ   XHI_SZ
#define RT_OFF   (XLO_OFF + XLO_SZ)                // rowT: s2 + 2e-6*rs + d*eps^2
#define RT_SZ    (3ull*4096ull*4ull)
#define CT_OFF   (RT_OFF + RT_SZ)                  // colT: s2 - 2e-6*rs
#define CT_SZ    (3ull*4096ull*4ull)
#define G_OFF    (CT_OFF + CT_SZ)
#define G_SZ     (3ull*4096ull*4096ull*4ull)       // 201326592
#define ACC_OFF  (G_OFF + G_SZ)
#define WS_NEEDED (ACC_OFF + 64ull)

// ---------------- Threefry-2x32 (JAX-exact) ----------------
__host__ __device__ __forceinline__ void tf2x32(uint32_t k0, uint32_t k1,
                                                uint32_t x0, uint32_t x1,
                                                uint32_t* o0, uint32_t* o1) {
  uint32_t ks2 = k0 ^ k1 ^ 0x1BD11BDAu;
  x0 += k0; x1 += k1;
#define TFR(r) { x0 += x1; x1 = (x1 << (r)) | (x1 >> (32 - (r))); x1 ^= x0; }
  TFR(13) TFR(15) TFR(26) TFR(6)
  x0 += k1; x1 += ks2 + 1u;
  TFR(17) TFR(29) TFR(16) TFR(24)
  x0 += ks2; x1 += k0 + 2u;
  TFR(13) TFR(15) TFR(26) TFR(6)
  x0 += k0; x1 += k1 + 3u;
  TFR(17) TFR(29) TFR(16) TFR(24)
  x0 += k1; x1 += ks2 + 4u;
  TFR(13) TFR(15) TFR(26) TFR(6)
  x0 += ks2; x1 += k0 + 5u;
#undef TFR
  *o0 = x0; *o1 = x1;
}

struct Keys { uint32_t k[6]; };

// ---------------- normalize + bf16 hi/lo split: one block per row ----------------
__global__ __launch_bounds__(128) void norm_kernel(const float* __restrict__ X,
                                                   __bf16* __restrict__ Xhi,
                                                   __bf16* __restrict__ Xlo,
                                                   float* __restrict__ rowT,
                                                   float* __restrict__ colT) {
  const int row = blockIdx.x;
  const int tid = threadIdx.x;
  const int lane = tid & 63, wid = tid >> 6;
  const float4 v = *(const float4*)(X + (size_t)row * NDIM + tid * 4);
  float ss = v.x*v.x + v.y*v.y + v.z*v.z + v.w*v.w;
  #pragma unroll
  for (int off = 32; off; off >>= 1) ss += __shfl_down(ss, off);
  __shared__ float sw[2];
  if (lane == 0) sw[wid] = ss;
  __syncthreads();
  const float tot = sw[0] + sw[1];
  const float den = fmaxf(sqrtf(tot), 1e-12f);
  float n[4];
  n[0] = v.x / den; n[1] = v.y / den; n[2] = v.z / den; n[3] = v.w / den;

  __bf16 hi[4], lo[4];
  #pragma unroll
  for (int e = 0; e < 4; ++e) {
    hi[e] = (__bf16)n[e];
    lo[e] = (__bf16)(n[e] - (float)hi[e]);
  }
  *(ushort4*)(Xhi + (size_t)row * NDIM + tid * 4) = *(ushort4*)hi;
  *(ushort4*)(Xlo + (size_t)row * NDIM + tid * 4) = *(ushort4*)lo;

  float ps = n[0] + n[1] + n[2] + n[3];
  float p2 = n[0]*n[0] + n[1]*n[1] + n[2]*n[2] + n[3]*n[3];
  #pragma unroll
  for (int off = 32; off; off >>= 1) { ps += __shfl_down(ps, off); p2 += __shfl_down(p2, off); }
  __shared__ float sw2[4];
  if (lane == 0) { sw2[wid] = ps; sw2[2 + wid] = p2; }
  __syncthreads();
  if (tid == 0) {
    const float rs = sw2[0] + sw2[1];
    const float s2 = sw2[2] + sw2[3];
    rowT[row] = s2 + 2e-6f * rs + 5.12e-10f;   // s2_i + 2eps*rs_i + d*eps^2
    colT[row] = s2 - 2e-6f * rs;               // s2_j - 2eps*rs_j
  }
}

// ---------------- split-bf16 MFMA SYRK, flattened triangular grid over 3 views ----------------
// tile 128x128, 4 waves (64x64 each), BK=64, K'=1536 (A'=[hi,hi,lo], B'=[hi,lo,hi]).
// XCD-swizzled block index; LDS-staged coalesced epilogue (normal + mirrored).
__global__ __launch_bounds__(256) void gemm_syrk_bf16(const __bf16* __restrict__ XhiBase,
                                                      const __bf16* __restrict__ XloBase,
                                                      float* __restrict__ CBase) {
  // XCD-aware bijective swizzle: 1584 % 8 == 0 -> consecutive logical tiles per XCD
  const int orig = blockIdx.x;
  const int bx = (orig & 7) * (1584 >> 3) + (orig >> 3);

  // decode view + triangular tile (bj >= bi), 528 tiles per view
  const int v = bx / 528;
  const int t = bx - v * 528;
  int bi = (int)((65.0f - sqrtf(4225.0f - 8.0f * (float)t)) * 0.5f);
  while ((bi + 1) * (65 - (bi + 1)) / 2 <= t) ++bi;
  while (bi * (65 - bi) / 2 > t) --bi;
  const int bj = bi + (t - bi * (65 - bi) / 2);

  const __bf16* __restrict__ Ahi = XhiBase + (size_t)v * NROW * NDIM;
  const __bf16* __restrict__ Alo = XloBase + (size_t)v * NROW * NDIM;
  float* __restrict__ C = CBase + ((size_t)v << 24);

  // unioned LDS: k-loop As/Bs (32 KB) ; epilogue float[64][136] / float[128][68] (34 KB)
  __shared__ __align__(16) char smemRaw[34816];
  __bf16 (*As)[64] = (__bf16 (*)[64])smemRaw;               // 128x64 bf16 = 16 KB
  __bf16 (*Bs)[64] = (__bf16 (*)[64])(smemRaw + 16384);     // 16 KB

  const int tid = threadIdx.x;
  const int lane = tid & 63;
  const int wid = tid >> 6;
  const int wr = wid >> 1, wc = wid & 1;

  f32x4 zero4 = {0.f, 0.f, 0.f, 0.f};
  f32x4 acc[4][4];
  #pragma unroll
  for (int m = 0; m < 4; ++m)
    #pragma unroll
    for (int n = 0; n < 4; ++n) acc[m][n] = zero4;

  const int lrow = lane >> 3;
  const int lcol = (lane & 7) * 8;
  const int fr = lane & 15;
  const int fk = (lane >> 4) * 8;

  for (int kt = 0; kt < 1536; kt += 64) {
    const int s = kt >> 9;
    const int colk = kt & 511;
    const __bf16* __restrict__ Asrc = (s < 2) ? Ahi : Alo;   // A' = [hi, hi, lo]
    const __bf16* __restrict__ Bsrc = (s == 1) ? Alo : Ahi;  // B' = [hi, lo, hi]
    #pragma unroll
    for (int p = 0; p < 4; ++p) {
      const int c = wid * 4 + p;
      const int trow = c * 8 + lrow;
      const __bf16* ga = Asrc + (((size_t)(bi * 128 + trow)) << 9) + colk + lcol;
      const __bf16* gb = Bsrc + (((size_t)(bj * 128 + trow)) << 9) + colk + lcol;
      __builtin_amdgcn_global_load_lds((const __attribute__((address_space(1))) void*)ga,
                                       (__attribute__((address_space(3))) void*)(smemRaw + c * 1024),
                                       16, 0, 0);
      __builtin_amdgcn_global_load_lds((const __attribute__((address_space(1))) void*)gb,
                                       (__attribute__((address_space(3))) void*)(smemRaw + 16384 + c * 1024),
                                       16, 0, 0);
    }
    __syncthreads();
    #pragma unroll
    for (int kk = 0; kk < 64; kk += 32) {
      bf16x8 af[4], bfr[4];
      #pragma unroll
      for (int m = 0; m < 4; ++m)
        af[m] = *(const bf16x8*)&As[wr * 64 + m * 16 + fr][kk + fk];
      #pragma unroll
      for (int n = 0; n < 4; ++n)
        bfr[n] = *(const bf16x8*)&Bs[wc * 64 + n * 16 + fr][kk + fk];
      #pragma unroll
      for (int m = 0; m < 4; ++m)
        #pragma unroll
        for (int n = 0; n < 4; ++n)
          acc[m][n] = __builtin_amdgcn_mfma_f32_16x16x32_bf16(af[m], bfr[n], acc[m][n], 0, 0, 0);
    }
    __syncthreads();
  }

  // ---- LDS-staged coalesced epilogue ----
  // C/D frag layout: col = lane&15, row = (lane>>4)*4 + reg  [m89/m91 verified]
  const int cl = lane & 15;
  const int rg = (lane >> 4) * 4;
  float (*Ls)[136] = (float (*)[136])smemRaw;   // 64 x 136 (row-chunk, padded, 16B-aligned rows)
  float (*Lt)[68]  = (float (*)[68])smemRaw;    // 128 x 68 (transposed chunk)

  __syncthreads();   // k-loop smem reads done before reuse
  #pragma unroll
  for (int r = 0; r < 2; ++r) {
    if (r) __syncthreads();
    if (wr == r) {
      #pragma unroll
      for (int m = 0; m < 4; ++m)
        #pragma unroll
        for (int n = 0; n < 4; ++n)
          #pragma unroll
          for (int q = 0; q < 4; ++q)
            Ls[m * 16 + rg + q][wc * 64 + n * 16 + cl] = acc[m][n][q];
    }
    __syncthreads();
    #pragma unroll
    for (int q = 0; q < 8; ++q) {
      const int idx = q * 256 + tid;       // 2048 float4 = 64 rows x 32
      const int row = idx >> 5, c4 = idx & 31;
      *(float4*)&C[(size_t)(bi * 128 + r * 64 + row) * NROW + bj * 128 + c4 * 4] =
          *(const float4*)&Ls[row][c4 * 4];
    }
    if (bi != bj) {
      __syncthreads();
      if (wr == r) {
        #pragma unroll
        for (int m = 0; m < 4; ++m)
          #pragma unroll
          for (int n = 0; n < 4; ++n)
            #pragma unroll
            for (int q = 0; q < 4; ++q)
              Lt[wc * 64 + n * 16 + cl][m * 16 + rg + q] = acc[m][n][q];
      }
      __syncthreads();
      #pragma unroll
      for (int q = 0; q < 8; ++q) {
        const int idx = q * 256 + tid;     // 2048 float4 = 128 rows x 16
        const int mrow = idx >> 4, c4 = idx & 15;
        *(float4*)&C[(size_t)(bj * 128 + mrow) * NROW + bi * 128 + r * 64 + c4 * 4] =
            *(const float4*)&Lt[mrow][c4 * 4];
      }
    }
  }
}

// ---------------- fused mask/scan/compact/sample/loss: one block per row, 512 threads ----------------
// Element mapping: thread t owns j in {p*2048 + t*4 + e : p<2, e<4} (all accesses float4).
__global__ __launch_bounds__(512, 8) void loss_kernel(const float* __restrict__ G,
                                                      const float* __restrict__ rowT,
                                                      const float* __restrict__ colT,
                                                      double* __restrict__ lossAcc,
                                                      unsigned long long* __restrict__ posAcc,
                                                      Keys keys) {
  __shared__ float sBuf[NROW];              // 16 KB: current view D row
  __shared__ unsigned short zlist[NROW];    // 8 KB: zero positions (sorted)
  __shared__ unsigned short plist[NROW];    // 8 KB: positive positions (sorted)
  __shared__ unsigned char nib[1024];       // zero-nibble per 4-element group
  __shared__ int sWaveTot[8];
  __shared__ float sLoss[8];

  const int i = blockIdx.x;
  const int tid = threadIdx.x;              // 0..511
  const int lane = tid & 63, wid = tid >> 6;  // wid 0..7

  // ---- phase 1: union mask straight from global (no LDS) ----
  {
    #pragma unroll
    for (int p = 0; p < 2; ++p) {
      const int j4 = p * 2048 + tid * 4;
      bool posb[4] = { false, false, false, false };
      #pragma unroll
      for (int v = 0; v < 3; ++v) {
        const float4 g = *(const float4*)(G + ((size_t)v << 24) + ((size_t)i << 12) + j4);
        posb[0] |= (g.x > THRS); posb[1] |= (g.y > THRS);
        posb[2] |= (g.z > THRS); posb[3] |= (g.w > THRS);
      }
      unsigned int z = 0;
      #pragma unroll
      for (int e = 0; e < 4; ++e) {
        const int j = j4 + e;
        const bool pos = posb[e] && (j != i);
        if (!pos) z |= (1u << e);
      }
      nib[p * 512 + tid] = (unsigned char)z;   // group index g = j/4 = p*512+tid
    }
  }
  __syncthreads();

  // ---- phase 2: block scan over 1024 groups (thread t owns groups 2t, 2t+1) ----
  const unsigned short nn2 = *(const unsigned short*)&nib[tid * 2];
  const unsigned int n0 = nn2 & 255u, n1 = nn2 >> 8;
  const int cz = __popc(n0) + __popc(n1);
  int inc = cz;
  #pragma unroll
  for (int off = 1; off < 64; off <<= 1) {
    const int s = __shfl_up(inc, off);
    if (lane >= off) inc += s;
  }
  if (lane == 63) sWaveTot[wid] = inc;
  __syncthreads();
  int base = inc - cz;
  for (int w = 0; w < wid; ++w) base += sWaveTot[w];
  const int cnt = sWaveTot[0] + sWaveTot[1] + sWaveTot[2] + sWaveTot[3] +
                  sWaveTot[4] + sWaveTot[5] + sWaveTot[6] + sWaveTot[7];
  {
    int zr = base;                     // zeros strictly before current j
    const unsigned int nq[2] = { n0, n1 };
    #pragma unroll
    for (int q = 0; q < 2; ++q) {
      const int jb = tid * 8 + q * 4;
      #pragma unroll
      for (int e = 0; e < 4; ++e) {
        const int j = jb + e;
        if ((nq[q] >> e) & 1) { zlist[zr] = (unsigned short)j; ++zr; }
        else                  { plist[j - zr] = (unsigned short)j; }
      }
    }
  }
  __syncthreads();

  const int npos = NROW - cnt;
  const float cntf = (float)cnt;
  const int cm1 = cnt - 1;
  float lossSum = 0.0f;

  // ---- phase 3: per view, stage+transform row then dense sampling over plist ----
  #pragma unroll
  for (int v = 0; v < 3; ++v) {
    const float rT = rowT[v * NROW + i];
    const float* __restrict__ cT = colT + v * NROW;
    const float* __restrict__ g = G + ((size_t)v << 24) + ((size_t)i << 12);
    #pragma unroll
    for (int p = 0; p < 2; ++p) {
      const int j4 = p * 2048 + tid * 4;
      const float4 gg = *(const float4*)(g + j4);
      const float4 ct = *(const float4*)(cT + j4);
      float4 d;
      d.x = sqrtf(fmaxf((rT + ct.x) - 2.0f * gg.x, 0.0f));
      d.y = sqrtf(fmaxf((rT + ct.y) - 2.0f * gg.y, 0.0f));
      d.z = sqrtf(fmaxf((rT + ct.z) - 2.0f * gg.z, 0.0f));
      d.w = sqrtf(fmaxf((rT + ct.w) - 2.0f * gg.w, 0.0f));
      *(float4*)&sBuf[j4] = d;
    }
    __syncthreads();

    const uint32_t fk0 = keys.k[2 * v], fk1 = keys.k[2 * v + 1];
    const uint32_t tbase = (uint32_t)i * 4096u;
    for (int k = tid; k < npos; k += 512) {
      const int j = plist[k];
      const uint32_t t32 = tbase + (uint32_t)j;
      uint32_t y0, y1, bits;
      if (i < 2048) { tf2x32(fk0, fk1, t32, t32 + 8388608u, &y0, &y1); bits = y0; }
      else          { tf2x32(fk0, fk1, t32 - 8388608u, t32, &y0, &y1); bits = y1; }
      const float u = __uint_as_float((bits >> 9) | 0x3F800000u) - 1.0f;
      int r = (int)(u * cntf);
      r = min(r, cm1);
      const int n = zlist[r];
      lossSum += fmaxf(sBuf[j] - sBuf[n] + 1.0f, 0.0f);
    }
    __syncthreads();   // before next view overwrites sBuf
  }

  // ---- block reduce ----
  #pragma unroll
  for (int off = 32; off; off >>= 1) lossSum += __shfl_down(lossSum, off);
  if (lane == 0) sLoss[wid] = lossSum;
  __syncthreads();
  if (tid == 0) {
    double tot = 0.0;
    #pragma unroll
    for (int w = 0; w < 8; ++w) tot += (double)sLoss[w];
    atomicAdd(lossAcc, tot);
    atomicAdd(posAcc, (unsigned long long)npos);
  }
}

__global__ void finalize_kernel(const double* __restrict__ lossAcc,
                                const unsigned long long* __restrict__ posAcc,
                                float* __restrict__ out) {
  if (threadIdx.x == 0 && blockIdx.x == 0) {
    out[0] = (float)(lossAcc[0] / (double)posAcc[0]);
  }
}

// ---------------- launch ----------------
extern "C" void kernel_launch(void* const* d_in, const int* in_sizes, int n_in,
                              void* d_out, int out_size, void* d_ws, size_t ws_size,
                              hipStream_t stream) {
  if (ws_size < WS_NEEDED) return;

  const float* Xs[3] = { (const float*)d_in[0], (const float*)d_in[1], (const float*)d_in[2] };
  char* ws = (char*)d_ws;
  __bf16* Xhi = (__bf16*)(ws + XHI_OFF);
  __bf16* Xlo = (__bf16*)(ws + XLO_OFF);
  float* rowT = (float*)(ws + RT_OFF);
  float* colT = (float*)(ws + CT_OFF);
  float* G  = (float*)(ws + G_OFF);
  double* lossAcc = (double*)(ws + ACC_OFF);
  unsigned long long* posAcc = (unsigned long long*)(ws + ACC_OFF + 8);
  float* out = (float*)d_out;

  hipMemsetAsync(ws + ACC_OFF, 0, 16, stream);

  for (int v = 0; v < 3; ++v)
    norm_kernel<<<NROW, 128, 0, stream>>>(Xs[v],
                                          Xhi + (size_t)v * NROW * NDIM,
                                          Xlo + (size_t)v * NROW * NDIM,
                                          rowT + v * NROW, colT + v * NROW);

  gemm_syrk_bf16<<<3 * 528, 256, 0, stream>>>(Xhi, Xlo, G);

  Keys keys;
  for (uint32_t v = 0; v < 3; ++v) {
    uint32_t y0, y1;
    tf2x32(0u, 42u, 0u, v, &y0, &y1);
    keys.k[2 * v] = y0; keys.k[2 * v + 1] = y1;
  }

  loss_kernel<<<NROW, 512, 0, stream>>>(G, rowT, colT, lossAcc, posAcc, keys);
  finalize_kernel<<<1, 1, 0, stream>>>(lossAcc, posAcc, out);
}